// Round 6
// baseline (124.368 us; speedup 1.0000x reference)
//
#include <hip/hip_runtime.h>
#include <hip/hip_bf16.h>

// BMSampling: out[bc, e] = X[bc, left(e)]*wl(e) + X[bc, right(e)]*wr(e)
// (the [100, 320000] weight matrix is analytically sparse: <=2 linear-interp
// taps per column e=(k,j,i)). Single fused kernel: each thread owns FOUR
// consecutive e (one float4 store), computes the 4 fp64 tap chains inline
// (bit-matching numpy, fp-contract OFF), then streams 32 bc rows.
//
// Round 6 change: PLAIN stores instead of nontemporal. r3/r4/r5 showed the
// kernel is insensitive to store width and LDS conflicts, plateauing ~26%
// above the pure-store floor; the remaining store-path difference vs the
// 6.8 TB/s fillBuffer baseline is the nt flag (suspected to forfeit L2
// write-coalescing/writeback efficiency). Nothing in L2 needs protecting
// (read set = 205 KB of X).

#define T_DIM 100
#define N_SMP 32
#define D_PROP 100
#define NKJI (N_SMP * D_PROP * T_DIM)   // 320000 columns
#define NF4 (NKJI / 4)                  // 80000 float4 per bc row
#define BC_TOTAL 512                    // B*C = 4*128
#define BC_CHUNK 32                     // bc rows per block (LDS: 12.8 KB)

typedef float f4 __attribute__((ext_vector_type(4)));

__global__ __launch_bounds__(256) void bms_fused(const float* __restrict__ X,
                                                 f4* __restrict__ out) {
    __shared__ float xs[BC_CHUNK * T_DIM];              // 12.8 KB
    const int bc0 = blockIdx.y * BC_CHUNK;

    // Stage X chunk (contiguous, 16B-aligned: bc0*400B % 16 == 0).
    {
        const f4* src = reinterpret_cast<const f4*>(X + bc0 * T_DIM);
        f4* dst = reinterpret_cast<f4*>(xs);
        for (int idx = threadIdx.x; idx < (BC_CHUNK * T_DIM) / 4; idx += 256)
            dst[idx] = src[idx];
    }
    __syncthreads();

    const int t4 = blockIdx.x * 256 + threadIdx.x;      // float4 index
    if (t4 >= NF4) return;                              // only last x-block

    // Per-element taps for the 4 consecutive e values (4 independent chains;
    // they can straddle a j boundary, so each recomputes i,j,k).
    float wl[4], wr[4];
    int   lt[4], rt[4];
    {
        // numpy computes xp = xmin_ext + k*bin_size as separate fp64 mul+add.
        // hipcc's default -ffp-contract=fast would fuse into one FMA, flipping
        // floor/ceil at exact-integer xp (where the reference weight is 2.0).
        #pragma clang fp contract(off)
        #pragma unroll 4
        for (int c = 0; c < 4; ++c) {
            const int e = t4 * 4 + c;
            const int i = e % T_DIM;
            const int j = (e / T_DIM) % D_PROP;
            const int k = e / (T_DIM * D_PROP);
            wl[c] = 0.0f; wr[c] = 0.0f; lt[c] = 0; rt[c] = 0;
            if (i + j <= T_DIM - 2) {                   // i+j <= 98
                int length = (j + 1) - i;               // can be negative
                double xmin_ext = (double)i - (double)length * 0.5;
                double xmax_ext = (double)(j + 1) + (double)length * 0.5;
                double bin_size = (xmax_ext - xmin_ext) / (double)(N_SMP - 1);
                double kb = (double)k * bin_size;       // separate mul...
                double xp = xmin_ext + kb;              // ...then add (no FMA)
                if (xp >= 0.0 && xp <= (double)(T_DIM - 1)) {
                    double fl = floor(xp);
                    double cl = ceil(xp);
                    lt[c] = (int)fl;
                    rt[c] = (int)cl;
                    wl[c] = (float)(1.0 - (xp - fl));
                    wr[c] = (float)(1.0 - (cl - xp));
                }
            }
        }
    }

    const float* x = xs;
    f4* o = out + (size_t)bc0 * NF4 + t4;
    #pragma unroll 8
    for (int b = 0; b < BC_CHUNK; ++b) {
        f4 v;
        v.x = x[lt[0]] * wl[0] + x[rt[0]] * wr[0];
        v.y = x[lt[1]] * wl[1] + x[rt[1]] * wr[1];
        v.z = x[lt[2]] * wl[2] + x[rt[2]] * wr[2];
        v.w = x[lt[3]] * wl[3] + x[rt[3]] * wr[3];
        *o = v;                                         // plain store (no nt)
        x += T_DIM;
        o += NF4;
    }
}

extern "C" void kernel_launch(void* const* d_in, const int* in_sizes, int n_in,
                              void* d_out, int out_size, void* d_ws, size_t ws_size,
                              hipStream_t stream) {
    const float* X = (const float*)d_in[0];   // [4,128,100] fp32
    f4* out = (f4*)d_out;                     // [4,128,32,100,100] fp32

    // 80000 float4 per row -> 313 blocks (last block 50% active), 16 bc chunks.
    dim3 grid((NF4 + 255) / 256, BC_TOTAL / BC_CHUNK);
    bms_fused<<<grid, 256, 0, stream>>>(X, out);
}

// Round 7
// 122.870 us; speedup vs baseline: 1.0122x; 1.0122x over previous
//
#include <hip/hip_runtime.h>
#include <hip/hip_bf16.h>

// BMSampling: out[bc, e] = X[bc, lt(e)]*wl(e) + X[bc, lt(e)+1]*wr(e)
// (the [100, 320000] weight matrix is analytically sparse: <=2 linear-interp
// taps per column e=(k,j,i)). Fused kernel: each thread owns 4 consecutive e,
// computes fp64 taps inline (bit-matching numpy), streams 32 bc rows with
// nontemporal float4 stores.
//
// Round 7 changes:
//  - RIGHT-TAP FOLD: rt == lt+1 always, except exact-integer xp where both
//    taps hit the same slot (ref weight 2.0) -> fold wl+=wr, wr=0. Gather is
//    then the adjacent pair (x[lt], x[lt+1]) -> ds_read2_b32 merge halves
//    LDS instruction count. Pad slot initialized (0*garbage != NaN safety).
//  - SIMPLIFIED fp64 prologue using exact identities:
//      xmin_ext = (3i-j-1)/2                (exactly representable)
//      xmax_ext - xmin_ext = 2*length       (exact in fp64)
//    so only /31, *k, + carry rounding — bit-identical to numpy's chain.
//  - nt stores kept (best measured, r5).

#define T_DIM 100
#define N_SMP 32
#define D_PROP 100
#define NKJI (N_SMP * D_PROP * T_DIM)   // 320000 columns
#define NF4 (NKJI / 4)                  // 80000 float4 per bc row
#define BC_TOTAL 512                    // B*C = 4*128
#define BC_CHUNK 32                     // bc rows per block (LDS: 12.8 KB)

typedef float f4 __attribute__((ext_vector_type(4)));

__global__ __launch_bounds__(256) void bms_fused(const float* __restrict__ X,
                                                 f4* __restrict__ out) {
    __shared__ float xs[BC_CHUNK * T_DIM + 1];          // +1 pad for lt=99,b=31
    const int bc0 = blockIdx.y * BC_CHUNK;

    // Stage X chunk (contiguous, 16B-aligned) + init the pad slot.
    {
        const f4* src = reinterpret_cast<const f4*>(X + bc0 * T_DIM);
        f4* dst = reinterpret_cast<f4*>(xs);
        for (int idx = threadIdx.x; idx < (BC_CHUNK * T_DIM) / 4; idx += 256)
            dst[idx] = src[idx];
        if (threadIdx.x == 0) xs[BC_CHUNK * T_DIM] = 0.0f;
    }
    __syncthreads();

    const int t4 = blockIdx.x * 256 + threadIdx.x;      // float4 index
    if (t4 >= NF4) return;

    // Taps for 4 consecutive e. After the fold, the pair (x[lt], x[lt+1]) is
    // always the gather target; wr==0 whenever lt+1 would be invalid.
    float wl[4], wr[4];
    int   lt[4];
    {
        // numpy computes xp = xmin_ext + k*bin_size as separate fp64 mul+add;
        // -ffp-contract=fast would fuse into one FMA and flip floor/ceil at
        // exact-integer xp. Keep contraction off in this block.
        #pragma clang fp contract(off)
        #pragma unroll 4
        for (int c = 0; c < 4; ++c) {
            const int e = t4 * 4 + c;
            const int i = e % T_DIM;
            const int j = (e / T_DIM) % D_PROP;
            const int k = e / (T_DIM * D_PROP);
            wl[c] = 0.0f; wr[c] = 0.0f; lt[c] = 0;
            if (i + j <= T_DIM - 2) {                   // i+j <= 98
                const int length = (j + 1) - i;         // can be negative
                // exact: xmin_ext = i - length*0.5 = (3i - j - 1)/2
                double xmin_ext = (double)(3 * i - j - 1) * 0.5;
                // exact: (xmax_ext - xmin_ext) == 2*length; numpy's division
                // is the only rounded op: bin_size = fl(2*length / 31.0)
                double bin_size = (double)(2 * length) / (double)(N_SMP - 1);
                double kb = (double)k * bin_size;       // separate mul...
                double xp = xmin_ext + kb;              // ...then add (no FMA)
                if (xp >= 0.0 && xp <= (double)(T_DIM - 1)) {
                    double fl_ = floor(xp);
                    double cl_ = ceil(xp);
                    lt[c] = (int)fl_;
                    float a = (float)(1.0 - (xp - fl_));
                    float b = (float)(1.0 - (cl_ - xp));
                    if (cl_ == fl_) { wl[c] = a + b; wr[c] = 0.0f; }  // xp integer
                    else            { wl[c] = a;     wr[c] = b;    }  // rt = lt+1
                }
            }
        }
    }

    const float* x = xs;
    f4* o = out + (size_t)bc0 * NF4 + t4;
    #pragma unroll 8
    for (int b = 0; b < BC_CHUNK; ++b) {
        // Adjacent-pair gathers -> ds_read2_b32 (one LDS instr per pair).
        float a0 = x[lt[0]], b0 = x[lt[0] + 1];
        float a1 = x[lt[1]], b1 = x[lt[1] + 1];
        float a2 = x[lt[2]], b2 = x[lt[2] + 1];
        float a3 = x[lt[3]], b3 = x[lt[3] + 1];
        f4 v;
        v.x = a0 * wl[0] + b0 * wr[0];
        v.y = a1 * wl[1] + b1 * wr[1];
        v.z = a2 * wl[2] + b2 * wr[2];
        v.w = a3 * wl[3] + b3 * wr[3];
        __builtin_nontemporal_store(v, o);
        x += T_DIM;
        o += NF4;
    }
}

extern "C" void kernel_launch(void* const* d_in, const int* in_sizes, int n_in,
                              void* d_out, int out_size, void* d_ws, size_t ws_size,
                              hipStream_t stream) {
    const float* X = (const float*)d_in[0];   // [4,128,100] fp32
    f4* out = (f4*)d_out;                     // [4,128,32,100,100] fp32

    dim3 grid((NF4 + 255) / 256, BC_TOTAL / BC_CHUNK);  // (313, 16)
    bms_fused<<<grid, 256, 0, stream>>>(X, out);
}